// Round 8
// baseline (471.914 us; speedup 1.0000x reference)
//
#include <hip/hip_runtime.h>
#include <hip/hip_bf16.h>

// Problem constants
#define HH 64
#define WW 128
#define DD 48
#define CG 8
// Padded volume layout: [d 50][w 130][h 66][c 32]  (channels-last, h inner)
#define PD 50
#define PWp 130
#define PHp 66
#define ROW 2112                               // elems per (d,w) row = 66*32
#define PVOL ((size_t)PD * PWp * ROW)          // 13,728,000 elems
#define FEAT ((size_t)HH * WW * 256)
#define SLICE_E (6 * ROW)                      // 12672 elems = 25344 B

typedef __hip_bfloat16 bf16;
typedef __attribute__((ext_vector_type(8))) short short8;
typedef __attribute__((ext_vector_type(4))) float f32x4;

__device__ __forceinline__ void gload_lds16(const bf16* g, bf16* l) {
    __builtin_amdgcn_global_load_lds(
        (const __attribute__((address_space(1))) unsigned int*)g,
        (__attribute__((address_space(3))) unsigned int*)l, 16, 0, 0);
}

// ---------------------------------------------------------------------------
// Border zeroing of both padded volumes
// ---------------------------------------------------------------------------
#define BORDER_ELEMS 1145088
__global__ __launch_bounds__(256) void border_zero_kernel(bf16* __restrict__ volA,
                                                          bf16* __restrict__ volB) {
    size_t tid = (size_t)blockIdx.x * 256 + threadIdx.x;
    if (tid >= 2 * (size_t)BORDER_ELEMS) return;
    bf16* vol = (tid >= BORDER_ELEMS) ? volB : volA;
    size_t i = (tid >= BORDER_ELEMS) ? tid - BORDER_ELEMS : tid;
    size_t addr;
    if (i < 549120) {                       // d slices 0 and 49
        int dsl = (i < 274560) ? 0 : 49;
        size_t rem = i % 274560;
        addr = (size_t)dsl * PWp * ROW + rem;
    } else if (i < 751872) {                // w cols 0 and 129, d 1..48
        size_t j = i - 549120;
        int dd = (int)(j / 4224);
        int rr = (int)(j % 4224);
        int wcol = (rr < ROW) ? 0 : 129;
        int off = (rr < ROW) ? rr : rr - ROW;
        addr = ((size_t)(dd + 1) * PWp + wcol) * ROW + off;
    } else {                                // h rows 0 and 65, d 1..48, w 1..128
        size_t j = i - 751872;
        int dd = (int)(j >> 13);
        int rr = (int)(j & 8191);
        int w = rr >> 6;
        int e = rr & 63;
        int hrow = (e < 32) ? 0 : 65;
        addr = ((size_t)(dd + 1) * PWp + (w + 1)) * ROW + hrow * 32 + (e & 31);
    }
    vol[addr] = __float2bfloat16(0.f);
}

// ---------------------------------------------------------------------------
// Feature transpose: [256][64][128] f32 -> [64][128][256] f32
// ---------------------------------------------------------------------------
__global__ __launch_bounds__(256) void transpose_feat_kernel(
    const float* __restrict__ src, float* __restrict__ dst) {
    __shared__ float tile[32][257];
    int tid = threadIdx.x;
    int w0  = blockIdx.x * 32;
    int h   = blockIdx.y;

#pragma unroll
    for (int it = 0; it < 32; ++it) {
        int c = it * 8 + (tid >> 5);
        tile[tid & 31][c] =
            src[(size_t)c * (HH * WW) + h * WW + w0 + (tid & 31)];
    }
    __syncthreads();

    int c_l = tid & 63, wg = tid >> 6;
#pragma unroll
    for (int it = 0; it < 8; ++it) {
        int w_i = it * 4 + wg;
        float* dp = dst + ((size_t)h * WW + w0 + w_i) * 256;
#pragma unroll
        for (int cc = 0; cc < 256; cc += 64)
            dp[cc + c_l] = tile[w_i][cc + c_l];
    }
}

// ---------------------------------------------------------------------------
// Weight conversion (4 mid layers fused): fp32 [32][32][27] -> bf16 [tap][co][ci]
// ---------------------------------------------------------------------------
__global__ void convert_w_mid4_kernel(const float* __restrict__ s0,
                                      const float* __restrict__ s1,
                                      const float* __restrict__ s2,
                                      const float* __restrict__ s3,
                                      bf16* __restrict__ d0, bf16* __restrict__ d1,
                                      bf16* __restrict__ d2, bf16* __restrict__ d3) {
    int tid = blockIdx.x * 256 + threadIdx.x;
    if (tid >= 4 * 27648) return;
    int layer = tid / 27648;
    int t = tid % 27648;
    const float* src = layer == 0 ? s0 : layer == 1 ? s1 : layer == 2 ? s2 : s3;
    bf16* dst = layer == 0 ? d0 : layer == 1 ? d1 : layer == 2 ? d2 : d3;
    int tap = t >> 10, co = (t >> 5) & 31, ci = t & 31;
    dst[t] = __float2bfloat16(src[(co * 32 + ci) * 27 + tap]);
}

__global__ void convert_w_final_kernel(const float* __restrict__ src,
                                       bf16* __restrict__ dst) {
    int tid = blockIdx.x * 256 + threadIdx.x;
    if (tid >= 27 * 16 * 32) return;
    int tap = tid >> 9;
    int co  = (tid >> 5) & 15;
    int ci  = tid & 31;
    dst[tid] = (co == 0) ? __float2bfloat16(src[ci * 27 + tap])
                         : __float2bfloat16(0.f);
}

// ---------------------------------------------------------------------------
// Cost volume from channels-last features -> padded [d][w][h][c] bf16
// ---------------------------------------------------------------------------
__global__ __launch_bounds__(256) void build_vol_kernel(
    const float* __restrict__ Lt, const float* __restrict__ Rt,
    bf16* __restrict__ vol) {
    int g  = threadIdx.x & 31;
    int wq = threadIdx.x >> 5;
    int w  = blockIdx.x * 8 + wq;
    int h  = blockIdx.y;

    const float4* lp = (const float4*)(Lt + ((size_t)h * WW + w) * 256 + g * 8);
    float4 l0 = lp[0], l1 = lp[1];
    const float* Rrow = Rt + (size_t)h * WW * 256;

    bf16* outp = vol + ((size_t)1 * PWp + (w + 1)) * ROW + (h + 1) * 32 + g;
    for (int d = 0; d < DD; ++d) {
        int x = w - d;
        float s = 0.f;
        if (x >= 0) {
            const float4* rp = (const float4*)(Rrow + (size_t)x * 256 + g * 8);
            float4 r0 = rp[0], r1 = rp[1];
            s = l0.x * r0.x + l0.y * r0.y + l0.z * r0.z + l0.w * r0.w +
                l1.x * r1.x + l1.y * r1.y + l1.z * r1.z + l1.w * r1.w;
            s *= 0.125f;
        }
        outp[(size_t)d * PWp * ROW] = __float2bfloat16(s);
    }
}

// ---------------------------------------------------------------------------
// Mid conv, pipelined d-walk (r6 mapping, 8-wave blocks). Block = 512 thr /
// 8 waves = (w-quad, d-segment of 3) -- SAME data mapping as r6 (grid 512,
// 2 blocks/CU, full-h 25 KB slices, 76 KB ring). Wave = (h-half, w-column):
// M=32 (2 tiles) x N=32. Per step: compute from ring, stage ONE new slice.
// Swizzle involution f(s)=s^((s>>3)&3) on global source; reads use
// slot=(hh*4+kg)^((hh>>1)&3)  (verified r5/r6: 0 bank conflicts).
// ---------------------------------------------------------------------------
__global__ __launch_bounds__(512, 4) void conv_mid_kernel(
    const bf16* __restrict__ X, const bf16* __restrict__ Wb,
    const float* __restrict__ bias, bf16* __restrict__ Y) {
    __shared__ bf16 lds[3 * SLICE_E];
    int id   = blockIdx.x;
    int xcd  = id & 7;
    int r    = id >> 3;                  // 0..63
    int wq   = r & 31;
    int dseg = xcd * 2 + (r >> 5);       // blocks sharing slices land on same XCD
    int w0   = wq * 4;
    int d0   = dseg * 3;
    int tid  = threadIdx.x;
    int wv   = tid >> 6;                 // 0..7
    int lane = tid & 63;
    int arow = lane & 15;
    int kg   = lane >> 4;
    int wcol  = wv & 3;                  // w column within quad
    int hhalf = wv >> 2;                 // 0..1
    int h0    = hhalf * 32;

    // stage one slice (6 rows x 4224 B): wave-group (wv>>2) takes 3 rows
    auto stage = [&](int dslice, bf16* dst) {
        int wv2 = wv & 3;
#pragma unroll
        for (int rr = 0; rr < 3; ++rr) {
            int row = hhalf * 3 + rr;
            const bf16* base = X + ((size_t)dslice * PWp + (w0 + row)) * ROW;
            bf16* ldst = dst + row * ROW;
            int s = wv2 * 64 + lane;
            int gir = s ^ ((s >> 3) & 3);
            gload_lds16(base + gir * 8, ldst + wv2 * 512);
            if (wv2 == 0 && lane < 8) {
                int s2 = 256 + lane;
                int gir2 = s2 ^ ((s2 >> 3) & 3);
                gload_lds16(base + gir2 * 8, ldst + 2048);
            }
        }
    };

    bf16* p0 = lds;
    bf16* p1 = lds + SLICE_E;
    bf16* p2 = lds + 2 * SLICE_E;
    stage(d0 + 0, p0);
    stage(d0 + 1, p1);
    stage(d0 + 2, p2);
    __syncthreads();

    const short8* Wv = (const short8*)Wb;
    float bv0 = bias[arow];
    float bv1 = bias[arow + 16];

    for (int i = 0; i < 3; ++i) {
        f32x4 acc[2][2] = {};
#pragma unroll
        for (int dz = 0; dz < 3; ++dz) {
            const bf16* P = (dz == 0) ? p0 : (dz == 1) ? p1 : p2;
#pragma unroll
            for (int dx = 0; dx < 3; ++dx) {
                const bf16* Ar = P + (wcol + dx) * ROW;
#pragma unroll
                for (int dy = 0; dy < 3; ++dy) {
                    int tap = dz * 9 + dy * 3 + dx;
                    short8 b0 = Wv[tap * 128 + arow * 4 + kg];
                    short8 b1 = Wv[tap * 128 + 64 + arow * 4 + kg];
                    int hh = h0 + arow + dy;
                    int s0 = (hh * 4 + kg) ^ ((hh >> 1) & 3);
#pragma unroll
                    for (int t = 0; t < 2; ++t) {
                        short8 a = *(const short8*)(Ar + s0 * 8 + t * 512);
                        acc[t][0] = __builtin_amdgcn_mfma_f32_16x16x32_bf16(
                            a, b0, acc[t][0], 0, 0, 0);
                        acc[t][1] = __builtin_amdgcn_mfma_f32_16x16x32_bf16(
                            a, b1, acc[t][1], 0, 0, 0);
                    }
                }
            }
        }
        __syncthreads();                       // all waves done reading p0
        if (i < 2) stage(d0 + i + 3, p0);      // refill freed slot

        int d = d0 + i;
        bf16* Yp = Y + ((size_t)(d + 1) * PWp + (w0 + wcol + 1)) * ROW +
                   (h0 + 1) * 32;
#pragma unroll
        for (int t = 0; t < 2; ++t)
#pragma unroll
            for (int rr = 0; rr < 4; ++rr) {
                int o = t * 16 + kg * 4 + rr;
                float v0 = acc[t][0][rr] + bv0;
                float v1 = acc[t][1][rr] + bv1;
                v0 = fmaxf(v0, 0.f) + 0.2f * fminf(v0, 0.f);
                v1 = fmaxf(v1, 0.f) + 0.2f * fminf(v1, 0.f);
                Yp[o * 32 + arow]      = __float2bfloat16(v0);
                Yp[o * 32 + arow + 16] = __float2bfloat16(v1);
            }
        __syncthreads();                       // staged slice landed
        bf16* tswap = p0; p0 = p1; p1 = p2; p2 = tswap;
    }
}

// ---------------------------------------------------------------------------
// Final conv (32ch -> 1), same 8-wave structure. fp32 out [d][h][w].
// ---------------------------------------------------------------------------
__global__ __launch_bounds__(512, 4) void conv_final_kernel(
    const bf16* __restrict__ X, const bf16* __restrict__ Wb,
    const float* __restrict__ bias, float* __restrict__ out) {
    __shared__ bf16 lds[3 * SLICE_E];
    int id   = blockIdx.x;
    int xcd  = id & 7;
    int r    = id >> 3;
    int wq   = r & 31;
    int dseg = xcd * 2 + (r >> 5);
    int w0   = wq * 4;
    int d0   = dseg * 3;
    int tid  = threadIdx.x;
    int wv   = tid >> 6;
    int lane = tid & 63;
    int arow = lane & 15;
    int kg   = lane >> 4;
    int wcol  = wv & 3;
    int hhalf = wv >> 2;
    int h0    = hhalf * 32;

    auto stage = [&](int dslice, bf16* dst) {
        int wv2 = wv & 3;
#pragma unroll
        for (int rr = 0; rr < 3; ++rr) {
            int row = hhalf * 3 + rr;
            const bf16* base = X + ((size_t)dslice * PWp + (w0 + row)) * ROW;
            bf16* ldst = dst + row * ROW;
            int s = wv2 * 64 + lane;
            int gir = s ^ ((s >> 3) & 3);
            gload_lds16(base + gir * 8, ldst + wv2 * 512);
            if (wv2 == 0 && lane < 8) {
                int s2 = 256 + lane;
                int gir2 = s2 ^ ((s2 >> 3) & 3);
                gload_lds16(base + gir2 * 8, ldst + 2048);
            }
        }
    };

    bf16* p0 = lds;
    bf16* p1 = lds + SLICE_E;
    bf16* p2 = lds + 2 * SLICE_E;
    stage(d0 + 0, p0);
    stage(d0 + 1, p1);
    stage(d0 + 2, p2);
    __syncthreads();

    const short8* Wv = (const short8*)Wb;
    float bv = bias[0];

    for (int i = 0; i < 3; ++i) {
        f32x4 acc[2] = {};
#pragma unroll
        for (int dz = 0; dz < 3; ++dz) {
            const bf16* P = (dz == 0) ? p0 : (dz == 1) ? p1 : p2;
#pragma unroll
            for (int dx = 0; dx < 3; ++dx) {
                const bf16* Ar = P + (wcol + dx) * ROW;
#pragma unroll
                for (int dy = 0; dy < 3; ++dy) {
                    int tap = dz * 9 + dy * 3 + dx;
                    short8 b = Wv[tap * 64 + arow * 4 + kg];
                    int hh = h0 + arow + dy;
                    int s0 = (hh * 4 + kg) ^ ((hh >> 1) & 3);
#pragma unroll
                    for (int t = 0; t < 2; ++t) {
                        short8 a = *(const short8*)(Ar + s0 * 8 + t * 512);
                        acc[t] = __builtin_amdgcn_mfma_f32_16x16x32_bf16(
                            a, b, acc[t], 0, 0, 0);
                    }
                }
            }
        }
        __syncthreads();
        if (i < 2) stage(d0 + i + 3, p0);

        if (arow == 0) {
            int d = d0 + i;
#pragma unroll
            for (int t = 0; t < 2; ++t)
#pragma unroll
                for (int rr = 0; rr < 4; ++rr) {
                    int o = h0 + t * 16 + kg * 4 + rr;
                    out[((size_t)d * HH + o) * WW + (w0 + wcol)] = acc[t][rr] + bv;
                }
        }
        __syncthreads();
        bf16* tswap = p0; p0 = p1; p1 = p2; p2 = tswap;
    }
}

// ---------------------------------------------------------------------------
// Launch
// ---------------------------------------------------------------------------
extern "C" void kernel_launch(void* const* d_in, const int* in_sizes, int n_in,
                              void* d_out, int out_size, void* d_ws, size_t ws_size,
                              hipStream_t stream) {
    const float* left  = (const float*)d_in[0];
    const float* right = (const float*)d_in[1];
    const float* w0 = (const float*)d_in[2];
    const float* b0 = (const float*)d_in[3];
    const float* w1 = (const float*)d_in[4];
    const float* b1 = (const float*)d_in[5];
    const float* w2 = (const float*)d_in[6];
    const float* b2 = (const float*)d_in[7];
    const float* w3 = (const float*)d_in[8];
    const float* b3 = (const float*)d_in[9];
    const float* wf = (const float*)d_in[10];
    const float* bf = (const float*)d_in[11];

    bf16* volA = (bf16*)d_ws;
    bf16* volB = volA + PVOL;
    bf16* wb0  = volB + PVOL;
    bf16* wb1  = wb0 + 27648;
    bf16* wb2  = wb1 + 27648;
    bf16* wb3  = wb2 + 27648;
    bf16* wbf  = wb3 + 27648;                 // 13824 elems
    float* Lt  = (float*)(wbf + 13824 + 32);  // 16B-aligned
    float* Rt  = Lt + FEAT;

    border_zero_kernel<<<(2 * BORDER_ELEMS + 255) / 256, 256, 0, stream>>>(volA, volB);

    convert_w_mid4_kernel<<<432, 256, 0, stream>>>(w0, w1, w2, w3, wb0, wb1, wb2, wb3);
    convert_w_final_kernel<<<54, 256, 0, stream>>>(wf, wbf);

    transpose_feat_kernel<<<dim3(WW / 32, HH), 256, 0, stream>>>(left, Lt);
    transpose_feat_kernel<<<dim3(WW / 32, HH), 256, 0, stream>>>(right, Rt);

    build_vol_kernel<<<dim3(WW / 8, HH), 256, 0, stream>>>(Lt, Rt, volA);

    int grid = 512;   // 32 w-quads x 16 d-segments (r6 mapping), 2 blocks/CU
    conv_mid_kernel<<<grid, 512, 0, stream>>>(volA, wb0, b0, volB);
    conv_mid_kernel<<<grid, 512, 0, stream>>>(volB, wb1, b1, volA);
    conv_mid_kernel<<<grid, 512, 0, stream>>>(volA, wb2, b2, volB);
    conv_mid_kernel<<<grid, 512, 0, stream>>>(volB, wb3, b3, volA);
    conv_final_kernel<<<grid, 512, 0, stream>>>(volA, wbf, bf, (float*)d_out);
}

// Round 9
// 201.067 us; speedup vs baseline: 2.3470x; 2.3470x over previous
//
#include <hip/hip_runtime.h>
#include <hip/hip_bf16.h>

// Problem constants
#define HH 64
#define WW 128
#define DD 48
#define CG 8
// Padded volume layout: [d 50][w 130][h 66][c 32]  (channels-last, h inner)
#define PD 50
#define PWp 130
#define PHp 66
#define ROW 2112                               // elems per (d,w) row = 66*32
#define PVOL ((size_t)PD * PWp * ROW)          // 13,728,000 elems
#define FEAT ((size_t)HH * WW * 256)
#define SLICE_E (6 * ROW)                      // 12672 elems = 25344 B

typedef __hip_bfloat16 bf16;
typedef __attribute__((ext_vector_type(8))) short short8;
typedef __attribute__((ext_vector_type(4))) float f32x4;

__device__ __forceinline__ void gload_lds16(const bf16* g, bf16* l) {
    __builtin_amdgcn_global_load_lds(
        (const __attribute__((address_space(1))) unsigned int*)g,
        (__attribute__((address_space(3))) unsigned int*)l, 16, 0, 0);
}

// ---------------------------------------------------------------------------
// Border zeroing of both padded volumes
// ---------------------------------------------------------------------------
#define BORDER_ELEMS 1145088
__global__ __launch_bounds__(256) void border_zero_kernel(bf16* __restrict__ volA,
                                                          bf16* __restrict__ volB) {
    size_t tid = (size_t)blockIdx.x * 256 + threadIdx.x;
    if (tid >= 2 * (size_t)BORDER_ELEMS) return;
    bf16* vol = (tid >= BORDER_ELEMS) ? volB : volA;
    size_t i = (tid >= BORDER_ELEMS) ? tid - BORDER_ELEMS : tid;
    size_t addr;
    if (i < 549120) {                       // d slices 0 and 49
        int dsl = (i < 274560) ? 0 : 49;
        size_t rem = i % 274560;
        addr = (size_t)dsl * PWp * ROW + rem;
    } else if (i < 751872) {                // w cols 0 and 129, d 1..48
        size_t j = i - 549120;
        int dd = (int)(j / 4224);
        int rr = (int)(j % 4224);
        int wcol = (rr < ROW) ? 0 : 129;
        int off = (rr < ROW) ? rr : rr - ROW;
        addr = ((size_t)(dd + 1) * PWp + wcol) * ROW + off;
    } else {                                // h rows 0 and 65, d 1..48, w 1..128
        size_t j = i - 751872;
        int dd = (int)(j >> 13);
        int rr = (int)(j & 8191);
        int w = rr >> 6;
        int e = rr & 63;
        int hrow = (e < 32) ? 0 : 65;
        addr = ((size_t)(dd + 1) * PWp + (w + 1)) * ROW + hrow * 32 + (e & 31);
    }
    vol[addr] = __float2bfloat16(0.f);
}

// ---------------------------------------------------------------------------
// Feature transpose (L and R fused via blockIdx.z):
// [256][64][128] f32 -> [64][128][256] f32
// ---------------------------------------------------------------------------
__global__ __launch_bounds__(256) void transpose_feat_kernel(
    const float* __restrict__ L, const float* __restrict__ R,
    float* __restrict__ Lt, float* __restrict__ Rt) {
    __shared__ float tile[32][257];
    const float* src = blockIdx.z ? R : L;
    float* dst       = blockIdx.z ? Rt : Lt;
    int tid = threadIdx.x;
    int w0  = blockIdx.x * 32;
    int h   = blockIdx.y;

#pragma unroll
    for (int it = 0; it < 32; ++it) {
        int c = it * 8 + (tid >> 5);
        tile[tid & 31][c] =
            src[(size_t)c * (HH * WW) + h * WW + w0 + (tid & 31)];
    }
    __syncthreads();

    int c_l = tid & 63, wg = tid >> 6;
#pragma unroll
    for (int it = 0; it < 8; ++it) {
        int w_i = it * 4 + wg;
        float* dp = dst + ((size_t)h * WW + w0 + w_i) * 256;
#pragma unroll
        for (int cc = 0; cc < 256; cc += 64)
            dp[cc + c_l] = tile[w_i][cc + c_l];
    }
}

// ---------------------------------------------------------------------------
// Weight conversion (4 mid layers fused): fp32 [32][32][27] -> bf16 [tap][co][ci]
// ---------------------------------------------------------------------------
__global__ void convert_w_mid4_kernel(const float* __restrict__ s0,
                                      const float* __restrict__ s1,
                                      const float* __restrict__ s2,
                                      const float* __restrict__ s3,
                                      bf16* __restrict__ d0, bf16* __restrict__ d1,
                                      bf16* __restrict__ d2, bf16* __restrict__ d3) {
    int tid = blockIdx.x * 256 + threadIdx.x;
    if (tid >= 4 * 27648) return;
    int layer = tid / 27648;
    int t = tid % 27648;
    const float* src = layer == 0 ? s0 : layer == 1 ? s1 : layer == 2 ? s2 : s3;
    bf16* dst = layer == 0 ? d0 : layer == 1 ? d1 : layer == 2 ? d2 : d3;
    int tap = t >> 10, co = (t >> 5) & 31, ci = t & 31;
    dst[t] = __float2bfloat16(src[(co * 32 + ci) * 27 + tap]);
}

__global__ void convert_w_final_kernel(const float* __restrict__ src,
                                       bf16* __restrict__ dst) {
    int tid = blockIdx.x * 256 + threadIdx.x;
    if (tid >= 27 * 16 * 32) return;
    int tap = tid >> 9;
    int co  = (tid >> 5) & 15;
    int ci  = tid & 31;
    dst[tid] = (co == 0) ? __float2bfloat16(src[ci * 27 + tap])
                         : __float2bfloat16(0.f);
}

// ---------------------------------------------------------------------------
// Cost volume from channels-last features -> padded [d][w][h][c] bf16
// ---------------------------------------------------------------------------
__global__ __launch_bounds__(256) void build_vol_kernel(
    const float* __restrict__ Lt, const float* __restrict__ Rt,
    bf16* __restrict__ vol) {
    int g  = threadIdx.x & 31;
    int wq = threadIdx.x >> 5;
    int w  = blockIdx.x * 8 + wq;
    int h  = blockIdx.y;

    const float4* lp = (const float4*)(Lt + ((size_t)h * WW + w) * 256 + g * 8);
    float4 l0 = lp[0], l1 = lp[1];
    const float* Rrow = Rt + (size_t)h * WW * 256;

    bf16* outp = vol + ((size_t)1 * PWp + (w + 1)) * ROW + (h + 1) * 32 + g;
    for (int d = 0; d < DD; ++d) {
        int x = w - d;
        float s = 0.f;
        if (x >= 0) {
            const float4* rp = (const float4*)(Rrow + (size_t)x * 256 + g * 8);
            float4 r0 = rp[0], r1 = rp[1];
            s = l0.x * r0.x + l0.y * r0.y + l0.z * r0.z + l0.w * r0.w +
                l1.x * r1.x + l1.y * r1.y + l1.z * r1.z + l1.w * r1.w;
            s *= 0.125f;
        }
        outp[(size_t)d * PWp * ROW] = __float2bfloat16(s);
    }
}

// ---------------------------------------------------------------------------
// Mid conv, pipelined d-walk (EXACT r6 structure: 256 thr / 4 waves,
// grid 512 = (w-quad, d-segment of 3), full-h 25 KB slices, 76 KB ring,
// 2 blocks/CU). Wave = one w column, M=64 (4 tiles) x N=32. Per step:
// compute from ring, stage ONE new slice into freed slot.
// Swizzle involution f(s)=s^((s>>3)&3) on global source; reads use
// slot=(hh*4+kg)^((hh>>1)&3). Verified r5/r6: 0 bank conflicts.
// Added this round: s_setprio(1/0) around each per-tap MFMA cluster (T5).
// ---------------------------------------------------------------------------
__global__ __launch_bounds__(256, 2) void conv_mid_kernel(
    const bf16* __restrict__ X, const bf16* __restrict__ Wb,
    const float* __restrict__ bias, bf16* __restrict__ Y) {
    __shared__ bf16 lds[3 * SLICE_E];
    int id   = blockIdx.x;
    int xcd  = id & 7;
    int r    = id >> 3;                  // 0..63
    int wq   = r & 31;
    int dseg = xcd * 2 + (r >> 5);       // blocks sharing slices land on same XCD
    int w0   = wq * 4;
    int d0   = dseg * 3;
    int tid  = threadIdx.x;
    int wv   = tid >> 6;
    int lane = tid & 63;
    int arow = lane & 15;
    int kg   = lane >> 4;

    auto stage = [&](int dslice, bf16* dst) {
#pragma unroll
        for (int row = 0; row < 6; ++row) {
            const bf16* base = X + ((size_t)dslice * PWp + (w0 + row)) * ROW;
            bf16* ldst = dst + row * ROW;
            int s = wv * 64 + lane;
            int gir = s ^ ((s >> 3) & 3);
            gload_lds16(base + gir * 8, ldst + wv * 512);
            if (tid < 8) {
                int s2 = 256 + lane;
                int gir2 = s2 ^ ((s2 >> 3) & 3);
                gload_lds16(base + gir2 * 8, ldst + 2048);
            }
        }
    };

    bf16* p0 = lds;
    bf16* p1 = lds + SLICE_E;
    bf16* p2 = lds + 2 * SLICE_E;
    stage(d0 + 0, p0);
    stage(d0 + 1, p1);
    stage(d0 + 2, p2);
    __syncthreads();

    const short8* Wv = (const short8*)Wb;
    float bv0 = bias[arow];
    float bv1 = bias[arow + 16];

    for (int i = 0; i < 3; ++i) {
        f32x4 acc[4][2] = {};
#pragma unroll
        for (int dz = 0; dz < 3; ++dz) {
            const bf16* P = (dz == 0) ? p0 : (dz == 1) ? p1 : p2;
#pragma unroll
            for (int dx = 0; dx < 3; ++dx) {
                const bf16* Ar = P + (wv + dx) * ROW;
#pragma unroll
                for (int dy = 0; dy < 3; ++dy) {
                    int tap = dz * 9 + dy * 3 + dx;
                    short8 b0 = Wv[tap * 128 + arow * 4 + kg];
                    short8 b1 = Wv[tap * 128 + 64 + arow * 4 + kg];
                    int hh = arow + dy;
                    int s0 = (hh * 4 + kg) ^ ((hh >> 1) & 3);
                    __builtin_amdgcn_s_setprio(1);
#pragma unroll
                    for (int t = 0; t < 4; ++t) {
                        short8 a = *(const short8*)(Ar + s0 * 8 + t * 512);
                        acc[t][0] = __builtin_amdgcn_mfma_f32_16x16x32_bf16(
                            a, b0, acc[t][0], 0, 0, 0);
                        acc[t][1] = __builtin_amdgcn_mfma_f32_16x16x32_bf16(
                            a, b1, acc[t][1], 0, 0, 0);
                    }
                    __builtin_amdgcn_s_setprio(0);
                }
            }
        }
        __syncthreads();                       // all waves done reading p0
        if (i < 2) stage(d0 + i + 3, p0);      // refill freed slot

        int d = d0 + i;
        bf16* Yp = Y + (((size_t)(d + 1) * PWp + (w0 + wv + 1))) * ROW + 32;
#pragma unroll
        for (int t = 0; t < 4; ++t)
#pragma unroll
            for (int rr = 0; rr < 4; ++rr) {
                int o = t * 16 + kg * 4 + rr;
                float v0 = acc[t][0][rr] + bv0;
                float v1 = acc[t][1][rr] + bv1;
                v0 = fmaxf(v0, 0.f) + 0.2f * fminf(v0, 0.f);
                v1 = fmaxf(v1, 0.f) + 0.2f * fminf(v1, 0.f);
                Yp[o * 32 + arow]      = __float2bfloat16(v0);
                Yp[o * 32 + arow + 16] = __float2bfloat16(v1);
            }
        __syncthreads();                       // staged slice landed
        bf16* tswap = p0; p0 = p1; p1 = p2; p2 = tswap;
    }
}

// ---------------------------------------------------------------------------
// Final conv (32ch -> 1), EXACT r6 structure. fp32 out [d][h][w].
// ---------------------------------------------------------------------------
__global__ __launch_bounds__(256, 2) void conv_final_kernel(
    const bf16* __restrict__ X, const bf16* __restrict__ Wb,
    const float* __restrict__ bias, float* __restrict__ out) {
    __shared__ bf16 lds[3 * SLICE_E];
    int id   = blockIdx.x;
    int xcd  = id & 7;
    int r    = id >> 3;
    int wq   = r & 31;
    int dseg = xcd * 2 + (r >> 5);
    int w0   = wq * 4;
    int d0   = dseg * 3;
    int tid  = threadIdx.x;
    int wv   = tid >> 6;
    int lane = tid & 63;
    int arow = lane & 15;
    int kg   = lane >> 4;

    auto stage = [&](int dslice, bf16* dst) {
#pragma unroll
        for (int row = 0; row < 6; ++row) {
            const bf16* base = X + ((size_t)dslice * PWp + (w0 + row)) * ROW;
            bf16* ldst = dst + row * ROW;
            int s = wv * 64 + lane;
            int gir = s ^ ((s >> 3) & 3);
            gload_lds16(base + gir * 8, ldst + wv * 512);
            if (tid < 8) {
                int s2 = 256 + lane;
                int gir2 = s2 ^ ((s2 >> 3) & 3);
                gload_lds16(base + gir2 * 8, ldst + 2048);
            }
        }
    };

    bf16* p0 = lds;
    bf16* p1 = lds + SLICE_E;
    bf16* p2 = lds + 2 * SLICE_E;
    stage(d0 + 0, p0);
    stage(d0 + 1, p1);
    stage(d0 + 2, p2);
    __syncthreads();

    const short8* Wv = (const short8*)Wb;
    float bv = bias[0];

    for (int i = 0; i < 3; ++i) {
        f32x4 acc[4] = {};
#pragma unroll
        for (int dz = 0; dz < 3; ++dz) {
            const bf16* P = (dz == 0) ? p0 : (dz == 1) ? p1 : p2;
#pragma unroll
            for (int dx = 0; dx < 3; ++dx) {
                const bf16* Ar = P + (wv + dx) * ROW;
#pragma unroll
                for (int dy = 0; dy < 3; ++dy) {
                    int tap = dz * 9 + dy * 3 + dx;
                    short8 b = Wv[tap * 64 + arow * 4 + kg];
                    int hh = arow + dy;
                    int s0 = (hh * 4 + kg) ^ ((hh >> 1) & 3);
                    __builtin_amdgcn_s_setprio(1);
#pragma unroll
                    for (int t = 0; t < 4; ++t) {
                        short8 a = *(const short8*)(Ar + s0 * 8 + t * 512);
                        acc[t] = __builtin_amdgcn_mfma_f32_16x16x32_bf16(
                            a, b, acc[t], 0, 0, 0);
                    }
                    __builtin_amdgcn_s_setprio(0);
                }
            }
        }
        __syncthreads();
        if (i < 2) stage(d0 + i + 3, p0);

        if (arow == 0) {
            int d = d0 + i;
#pragma unroll
            for (int t = 0; t < 4; ++t)
#pragma unroll
                for (int rr = 0; rr < 4; ++rr) {
                    int o = t * 16 + kg * 4 + rr;
                    out[((size_t)d * HH + o) * WW + (w0 + wv)] = acc[t][rr] + bv;
                }
        }
        __syncthreads();
        bf16* tswap = p0; p0 = p1; p1 = p2; p2 = tswap;
    }
}

// ---------------------------------------------------------------------------
// Launch
// ---------------------------------------------------------------------------
extern "C" void kernel_launch(void* const* d_in, const int* in_sizes, int n_in,
                              void* d_out, int out_size, void* d_ws, size_t ws_size,
                              hipStream_t stream) {
    const float* left  = (const float*)d_in[0];
    const float* right = (const float*)d_in[1];
    const float* w0 = (const float*)d_in[2];
    const float* b0 = (const float*)d_in[3];
    const float* w1 = (const float*)d_in[4];
    const float* b1 = (const float*)d_in[5];
    const float* w2 = (const float*)d_in[6];
    const float* b2 = (const float*)d_in[7];
    const float* w3 = (const float*)d_in[8];
    const float* b3 = (const float*)d_in[9];
    const float* wf = (const float*)d_in[10];
    const float* bf = (const float*)d_in[11];

    bf16* volA = (bf16*)d_ws;
    bf16* volB = volA + PVOL;
    bf16* wb0  = volB + PVOL;
    bf16* wb1  = wb0 + 27648;
    bf16* wb2  = wb1 + 27648;
    bf16* wb3  = wb2 + 27648;
    bf16* wbf  = wb3 + 27648;                 // 13824 elems
    float* Lt  = (float*)(wbf + 13824 + 32);  // 16B-aligned
    float* Rt  = Lt + FEAT;

    border_zero_kernel<<<(2 * BORDER_ELEMS + 255) / 256, 256, 0, stream>>>(volA, volB);

    convert_w_mid4_kernel<<<432, 256, 0, stream>>>(w0, w1, w2, w3, wb0, wb1, wb2, wb3);
    convert_w_final_kernel<<<54, 256, 0, stream>>>(wf, wbf);

    transpose_feat_kernel<<<dim3(WW / 32, HH, 2), 256, 0, stream>>>(left, right, Lt, Rt);

    build_vol_kernel<<<dim3(WW / 8, HH), 256, 0, stream>>>(Lt, Rt, volA);

    int grid = 512;   // 32 w-quads x 16 d-segments, all-resident (2 blocks/CU)
    conv_mid_kernel<<<grid, 256, 0, stream>>>(volA, wb0, b0, volB);
    conv_mid_kernel<<<grid, 256, 0, stream>>>(volB, wb1, b1, volA);
    conv_mid_kernel<<<grid, 256, 0, stream>>>(volA, wb2, b2, volB);
    conv_mid_kernel<<<grid, 256, 0, stream>>>(volB, wb3, b3, volA);
    conv_final_kernel<<<grid, 256, 0, stream>>>(volA, wbf, bf, (float*)d_out);
}

// Round 10
// 188.685 us; speedup vs baseline: 2.5011x; 1.0656x over previous
//
#include <hip/hip_runtime.h>
#include <hip/hip_bf16.h>

// Problem constants
#define HH 64
#define WW 128
#define DD 48
#define CG 8
// Padded volume layout: [d 50][w 130][h 66][c 32]  (channels-last, h inner)
#define PD 50
#define PWp 130
#define PHp 66
#define ROW 2112                               // elems per (d,w) row = 66*32
#define PVOL ((size_t)PD * PWp * ROW)          // 13,728,000 elems
#define FEAT ((size_t)HH * WW * 256)
#define SLICE_E (6 * ROW)                      // 12672 elems = 25344 B

typedef __hip_bfloat16 bf16;
typedef __attribute__((ext_vector_type(8))) short short8;
typedef __attribute__((ext_vector_type(4))) float f32x4;

__device__ __forceinline__ void gload_lds16(const bf16* g, bf16* l) {
    __builtin_amdgcn_global_load_lds(
        (const __attribute__((address_space(1))) unsigned int*)g,
        (__attribute__((address_space(3))) unsigned int*)l, 16, 0, 0);
}

// ---------------------------------------------------------------------------
// Border zeroing of both padded volumes
// ---------------------------------------------------------------------------
#define BORDER_ELEMS 1145088
__global__ __launch_bounds__(256) void border_zero_kernel(bf16* __restrict__ volA,
                                                          bf16* __restrict__ volB) {
    size_t tid = (size_t)blockIdx.x * 256 + threadIdx.x;
    if (tid >= 2 * (size_t)BORDER_ELEMS) return;
    bf16* vol = (tid >= BORDER_ELEMS) ? volB : volA;
    size_t i = (tid >= BORDER_ELEMS) ? tid - BORDER_ELEMS : tid;
    size_t addr;
    if (i < 549120) {                       // d slices 0 and 49
        int dsl = (i < 274560) ? 0 : 49;
        size_t rem = i % 274560;
        addr = (size_t)dsl * PWp * ROW + rem;
    } else if (i < 751872) {                // w cols 0 and 129, d 1..48
        size_t j = i - 549120;
        int dd = (int)(j / 4224);
        int rr = (int)(j % 4224);
        int wcol = (rr < ROW) ? 0 : 129;
        int off = (rr < ROW) ? rr : rr - ROW;
        addr = ((size_t)(dd + 1) * PWp + wcol) * ROW + off;
    } else {                                // h rows 0 and 65, d 1..48, w 1..128
        size_t j = i - 751872;
        int dd = (int)(j >> 13);
        int rr = (int)(j & 8191);
        int w = rr >> 6;
        int e = rr & 63;
        int hrow = (e < 32) ? 0 : 65;
        addr = ((size_t)(dd + 1) * PWp + (w + 1)) * ROW + hrow * 32 + (e & 31);
    }
    vol[addr] = __float2bfloat16(0.f);
}

// ---------------------------------------------------------------------------
// Feature transpose (L and R fused via blockIdx.z):
// [256][64][128] f32 -> [64][128][256] f32
// ---------------------------------------------------------------------------
__global__ __launch_bounds__(256) void transpose_feat_kernel(
    const float* __restrict__ L, const float* __restrict__ R,
    float* __restrict__ Lt, float* __restrict__ Rt) {
    __shared__ float tile[32][257];
    const float* src = blockIdx.z ? R : L;
    float* dst       = blockIdx.z ? Rt : Lt;
    int tid = threadIdx.x;
    int w0  = blockIdx.x * 32;
    int h   = blockIdx.y;

#pragma unroll
    for (int it = 0; it < 32; ++it) {
        int c = it * 8 + (tid >> 5);
        tile[tid & 31][c] =
            src[(size_t)c * (HH * WW) + h * WW + w0 + (tid & 31)];
    }
    __syncthreads();

    int c_l = tid & 63, wg = tid >> 6;
#pragma unroll
    for (int it = 0; it < 8; ++it) {
        int w_i = it * 4 + wg;
        float* dp = dst + ((size_t)h * WW + w0 + w_i) * 256;
#pragma unroll
        for (int cc = 0; cc < 256; cc += 64)
            dp[cc + c_l] = tile[w_i][cc + c_l];
    }
}

// ---------------------------------------------------------------------------
// Weight conversion (4 mid layers fused): fp32 [32][32][27] -> bf16 [tap][co][ci]
// ---------------------------------------------------------------------------
__global__ void convert_w_mid4_kernel(const float* __restrict__ s0,
                                      const float* __restrict__ s1,
                                      const float* __restrict__ s2,
                                      const float* __restrict__ s3,
                                      bf16* __restrict__ d0, bf16* __restrict__ d1,
                                      bf16* __restrict__ d2, bf16* __restrict__ d3) {
    int tid = blockIdx.x * 256 + threadIdx.x;
    if (tid >= 4 * 27648) return;
    int layer = tid / 27648;
    int t = tid % 27648;
    const float* src = layer == 0 ? s0 : layer == 1 ? s1 : layer == 2 ? s2 : s3;
    bf16* dst = layer == 0 ? d0 : layer == 1 ? d1 : layer == 2 ? d2 : d3;
    int tap = t >> 10, co = (t >> 5) & 31, ci = t & 31;
    dst[t] = __float2bfloat16(src[(co * 32 + ci) * 27 + tap]);
}

__global__ void convert_w_final_kernel(const float* __restrict__ src,
                                       bf16* __restrict__ dst) {
    int tid = blockIdx.x * 256 + threadIdx.x;
    if (tid >= 27 * 16 * 32) return;
    int tap = tid >> 9;
    int co  = (tid >> 5) & 15;
    int ci  = tid & 31;
    dst[tid] = (co == 0) ? __float2bfloat16(src[ci * 27 + tap])
                         : __float2bfloat16(0.f);
}

// ---------------------------------------------------------------------------
// Cost volume from channels-last features -> padded [d][w][h][c] bf16
// ---------------------------------------------------------------------------
__global__ __launch_bounds__(256) void build_vol_kernel(
    const float* __restrict__ Lt, const float* __restrict__ Rt,
    bf16* __restrict__ vol) {
    int g  = threadIdx.x & 31;
    int wq = threadIdx.x >> 5;
    int w  = blockIdx.x * 8 + wq;
    int h  = blockIdx.y;

    const float4* lp = (const float4*)(Lt + ((size_t)h * WW + w) * 256 + g * 8);
    float4 l0 = lp[0], l1 = lp[1];
    const float* Rrow = Rt + (size_t)h * WW * 256;

    bf16* outp = vol + ((size_t)1 * PWp + (w + 1)) * ROW + (h + 1) * 32 + g;
    for (int d = 0; d < DD; ++d) {
        int x = w - d;
        float s = 0.f;
        if (x >= 0) {
            const float4* rp = (const float4*)(Rrow + (size_t)x * 256 + g * 8);
            float4 r0 = rp[0], r1 = rp[1];
            s = l0.x * r0.x + l0.y * r0.y + l0.z * r0.z + l0.w * r0.w +
                l1.x * r1.x + l1.y * r1.y + l1.z * r1.z + l1.w * r1.w;
            s *= 0.125f;
        }
        outp[(size_t)d * PWp * ROW] = __float2bfloat16(s);
    }
}

// ---------------------------------------------------------------------------
// Mid conv, pipelined d-walk (EXACT r6 block/grid/LDS/stage structure:
// 256 thr / 4 waves, grid 512 = (w-quad, d-segment of 3), full-h 25 KB
// slices, 76 KB ring, 2 blocks/CU). Wave = one w column, M=64 x N=32.
// NEW (r10): dz-split async refill -- compute dz=0 (only reader of ring
// slot p0), barrier, ISSUE refill into p0, then compute dz=1,2 + epilogue
// before the end barrier drains vmcnt. Stage latency hides under 2/3 of
// the step's compute instead of under nothing.
// Swizzle involution f(s)=s^((s>>3)&3) on global source; reads use
// slot=(hh*4+kg)^((hh>>1)&3). Verified r5/r6: 0 bank conflicts.
// ---------------------------------------------------------------------------
__global__ __launch_bounds__(256, 2) void conv_mid_kernel(
    const bf16* __restrict__ X, const bf16* __restrict__ Wb,
    const float* __restrict__ bias, bf16* __restrict__ Y) {
    __shared__ bf16 lds[3 * SLICE_E];
    int id   = blockIdx.x;
    int xcd  = id & 7;
    int r    = id >> 3;                  // 0..63
    int wq   = r & 31;
    int dseg = xcd * 2 + (r >> 5);       // blocks sharing slices land on same XCD
    int w0   = wq * 4;
    int d0   = dseg * 3;
    int tid  = threadIdx.x;
    int wv   = tid >> 6;
    int lane = tid & 63;
    int arow = lane & 15;
    int kg   = lane >> 4;

    auto stage = [&](int dslice, bf16* dst) {
#pragma unroll
        for (int row = 0; row < 6; ++row) {
            const bf16* base = X + ((size_t)dslice * PWp + (w0 + row)) * ROW;
            bf16* ldst = dst + row * ROW;
            int s = wv * 64 + lane;
            int gir = s ^ ((s >> 3) & 3);
            gload_lds16(base + gir * 8, ldst + wv * 512);
            if (tid < 8) {
                int s2 = 256 + lane;
                int gir2 = s2 ^ ((s2 >> 3) & 3);
                gload_lds16(base + gir2 * 8, ldst + 2048);
            }
        }
    };

    bf16* p0 = lds;
    bf16* p1 = lds + SLICE_E;
    bf16* p2 = lds + 2 * SLICE_E;
    stage(d0 + 0, p0);
    stage(d0 + 1, p1);
    stage(d0 + 2, p2);
    __syncthreads();

    const short8* Wv = (const short8*)Wb;
    float bv0 = bias[arow];
    float bv1 = bias[arow + 16];

    for (int i = 0; i < 3; ++i) {
        f32x4 acc[4][2] = {};

        // accumulate one dz-slice worth of taps from ring slot P
        auto compute_dz = [&](const bf16* P, int dz) {
#pragma unroll
            for (int dx = 0; dx < 3; ++dx) {
                const bf16* Ar = P + (wv + dx) * ROW;
#pragma unroll
                for (int dy = 0; dy < 3; ++dy) {
                    int tap = dz * 9 + dy * 3 + dx;
                    short8 b0 = Wv[tap * 128 + arow * 4 + kg];
                    short8 b1 = Wv[tap * 128 + 64 + arow * 4 + kg];
                    int hh = arow + dy;
                    int s0 = (hh * 4 + kg) ^ ((hh >> 1) & 3);
#pragma unroll
                    for (int t = 0; t < 4; ++t) {
                        short8 a = *(const short8*)(Ar + s0 * 8 + t * 512);
                        acc[t][0] = __builtin_amdgcn_mfma_f32_16x16x32_bf16(
                            a, b0, acc[t][0], 0, 0, 0);
                        acc[t][1] = __builtin_amdgcn_mfma_f32_16x16x32_bf16(
                            a, b1, acc[t][1], 0, 0, 0);
                    }
                }
            }
        };

        // Phase A: dz=0 -- sole reader of p0
        compute_dz(p0, 0);
        __syncthreads();                       // all waves done with p0
        if (i < 2) stage(d0 + i + 3, p0);      // async refill into freed slot
        // Phase B: dz=1,2 -- stage latency hides under this
        compute_dz(p1, 1);
        compute_dz(p2, 2);

        int d = d0 + i;
        bf16* Yp = Y + (((size_t)(d + 1) * PWp + (w0 + wv + 1))) * ROW + 32;
#pragma unroll
        for (int t = 0; t < 4; ++t)
#pragma unroll
            for (int rr = 0; rr < 4; ++rr) {
                int o = t * 16 + kg * 4 + rr;
                float v0 = acc[t][0][rr] + bv0;
                float v1 = acc[t][1][rr] + bv1;
                v0 = fmaxf(v0, 0.f) + 0.2f * fminf(v0, 0.f);
                v1 = fmaxf(v1, 0.f) + 0.2f * fminf(v1, 0.f);
                Yp[o * 32 + arow]      = __float2bfloat16(v0);
                Yp[o * 32 + arow + 16] = __float2bfloat16(v1);
            }
        __syncthreads();                       // vmcnt(0) drained here: slice landed
        bf16* tswap = p0; p0 = p1; p1 = p2; p2 = tswap;
    }
}

// ---------------------------------------------------------------------------
// Final conv (32ch -> 1), same structure + dz-split async refill. fp32 out.
// ---------------------------------------------------------------------------
__global__ __launch_bounds__(256, 2) void conv_final_kernel(
    const bf16* __restrict__ X, const bf16* __restrict__ Wb,
    const float* __restrict__ bias, float* __restrict__ out) {
    __shared__ bf16 lds[3 * SLICE_E];
    int id   = blockIdx.x;
    int xcd  = id & 7;
    int r    = id >> 3;
    int wq   = r & 31;
    int dseg = xcd * 2 + (r >> 5);
    int w0   = wq * 4;
    int d0   = dseg * 3;
    int tid  = threadIdx.x;
    int wv   = tid >> 6;
    int lane = tid & 63;
    int arow = lane & 15;
    int kg   = lane >> 4;

    auto stage = [&](int dslice, bf16* dst) {
#pragma unroll
        for (int row = 0; row < 6; ++row) {
            const bf16* base = X + ((size_t)dslice * PWp + (w0 + row)) * ROW;
            bf16* ldst = dst + row * ROW;
            int s = wv * 64 + lane;
            int gir = s ^ ((s >> 3) & 3);
            gload_lds16(base + gir * 8, ldst + wv * 512);
            if (tid < 8) {
                int s2 = 256 + lane;
                int gir2 = s2 ^ ((s2 >> 3) & 3);
                gload_lds16(base + gir2 * 8, ldst + 2048);
            }
        }
    };

    bf16* p0 = lds;
    bf16* p1 = lds + SLICE_E;
    bf16* p2 = lds + 2 * SLICE_E;
    stage(d0 + 0, p0);
    stage(d0 + 1, p1);
    stage(d0 + 2, p2);
    __syncthreads();

    const short8* Wv = (const short8*)Wb;
    float bv = bias[0];

    for (int i = 0; i < 3; ++i) {
        f32x4 acc[4] = {};

        auto compute_dz = [&](const bf16* P, int dz) {
#pragma unroll
            for (int dx = 0; dx < 3; ++dx) {
                const bf16* Ar = P + (wv + dx) * ROW;
#pragma unroll
                for (int dy = 0; dy < 3; ++dy) {
                    int tap = dz * 9 + dy * 3 + dx;
                    short8 b = Wv[tap * 64 + arow * 4 + kg];
                    int hh = arow + dy;
                    int s0 = (hh * 4 + kg) ^ ((hh >> 1) & 3);
#pragma unroll
                    for (int t = 0; t < 4; ++t) {
                        short8 a = *(const short8*)(Ar + s0 * 8 + t * 512);
                        acc[t] = __builtin_amdgcn_mfma_f32_16x16x32_bf16(
                            a, b, acc[t], 0, 0, 0);
                    }
                }
            }
        };

        compute_dz(p0, 0);
        __syncthreads();
        if (i < 2) stage(d0 + i + 3, p0);
        compute_dz(p1, 1);
        compute_dz(p2, 2);

        if (arow == 0) {
            int d = d0 + i;
#pragma unroll
            for (int t = 0; t < 4; ++t)
#pragma unroll
                for (int rr = 0; rr < 4; ++rr) {
                    int o = t * 16 + kg * 4 + rr;
                    out[((size_t)d * HH + o) * WW + (w0 + wv)] = acc[t][rr] + bv;
                }
        }
        __syncthreads();
        bf16* tswap = p0; p0 = p1; p1 = p2; p2 = tswap;
    }
}

// ---------------------------------------------------------------------------
// Launch
// ---------------------------------------------------------------------------
extern "C" void kernel_launch(void* const* d_in, const int* in_sizes, int n_in,
                              void* d_out, int out_size, void* d_ws, size_t ws_size,
                              hipStream_t stream) {
    const float* left  = (const float*)d_in[0];
    const float* right = (const float*)d_in[1];
    const float* w0 = (const float*)d_in[2];
    const float* b0 = (const float*)d_in[3];
    const float* w1 = (const float*)d_in[4];
    const float* b1 = (const float*)d_in[5];
    const float* w2 = (const float*)d_in[6];
    const float* b2 = (const float*)d_in[7];
    const float* w3 = (const float*)d_in[8];
    const float* b3 = (const float*)d_in[9];
    const float* wf = (const float*)d_in[10];
    const float* bf = (const float*)d_in[11];

    bf16* volA = (bf16*)d_ws;
    bf16* volB = volA + PVOL;
    bf16* wb0  = volB + PVOL;
    bf16* wb1  = wb0 + 27648;
    bf16* wb2  = wb1 + 27648;
    bf16* wb3  = wb2 + 27648;
    bf16* wbf  = wb3 + 27648;                 // 13824 elems
    float* Lt  = (float*)(wbf + 13824 + 32);  // 16B-aligned
    float* Rt  = Lt + FEAT;

    border_zero_kernel<<<(2 * BORDER_ELEMS + 255) / 256, 256, 0, stream>>>(volA, volB);

    convert_w_mid4_kernel<<<432, 256, 0, stream>>>(w0, w1, w2, w3, wb0, wb1, wb2, wb3);
    convert_w_final_kernel<<<54, 256, 0, stream>>>(wf, wbf);

    transpose_feat_kernel<<<dim3(WW / 32, HH, 2), 256, 0, stream>>>(left, right, Lt, Rt);

    build_vol_kernel<<<dim3(WW / 8, HH), 256, 0, stream>>>(Lt, Rt, volA);

    int grid = 512;   // 32 w-quads x 16 d-segments, all-resident (2 blocks/CU)
    conv_mid_kernel<<<grid, 256, 0, stream>>>(volA, wb0, b0, volB);
    conv_mid_kernel<<<grid, 256, 0, stream>>>(volB, wb1, b1, volA);
    conv_mid_kernel<<<grid, 256, 0, stream>>>(volA, wb2, b2, volB);
    conv_mid_kernel<<<grid, 256, 0, stream>>>(volB, wb3, b3, volA);
    conv_final_kernel<<<grid, 256, 0, stream>>>(volA, wbf, bf, (float*)d_out);
}